// Round 6
// baseline (531.523 us; speedup 1.0000x reference)
//
#include <hip/hip_runtime.h>
#include <hip/hip_bf16.h>

#define NQ 12
#define NL 5
#define DIM 4096
#define BATCH 4096
#define TILE 128
#define BK 32
#define NIT (DIM / BK)                  // 128
#define NTILE (BATCH / TILE)            // 32
#define NBLK (NTILE * (NTILE + 1) / 2)  // 528
#define NXCD 8
#define CPX (NBLK / NXCD)               // 66, exact -> bijective swizzle

typedef __bf16 bf16x8 __attribute__((ext_vector_type(8)));
typedef float f32x16 __attribute__((ext_vector_type(16)));
typedef unsigned int u32x4 __attribute__((ext_vector_type(4)));
typedef unsigned int u32;
typedef unsigned short u16;

#define MFMA32(a, b, c) __builtin_amdgcn_mfma_f32_32x32x16_bf16(a, b, c, 0, 0, 0)

// float -> bf16 bits, round-to-nearest-even
__device__ static inline u16 f32_to_bf16_bits(float x) {
    u32 b = __builtin_bit_cast(u32, x);
    b += 0x7fffu + ((b >> 16) & 1u);
    return (u16)(b >> 16);
}

// async 16B global->LDS; HW writes wave-uniform lds base + lane*16.
__device__ static inline void async_copy16(const void* g, void* l) {
    __builtin_amdgcn_global_load_lds((const __attribute__((address_space(1))) u32*)g,
                                     (__attribute__((address_space(3))) u32*)l, 16, 0, 0);
}

// complex helpers
__device__ static inline float2 cmul(float2 m, float2 a) {
    return make_float2(m.x * a.x - m.y * a.y, m.x * a.y + m.y * a.x);
}
__device__ static inline float2 cadd(float2 a, float2 b) {
    return make_float2(a.x + b.x, a.y + b.y);
}

// tile index p (0..527) -> (bi, bj), bi <= bj
__device__ static inline void tile_of(int p, int* bi, int* bj) {
    int rem = p, b = 0;
    while (rem >= NTILE - b) { rem -= NTILE - b; ++b; }
    *bi = b; *bj = b + rem;
}

// ---------------------------------------------------------------------------
// Kernel A: batch-independent part (layers 0..3 full, layer 4 param gates).
// ---------------------------------------------------------------------------
__global__ __launch_bounds__(1024) void qnn_base(const float* __restrict__ params,
                                                 float2* __restrict__ psi1) {
    __shared__ float2 st[DIM];
    __shared__ float2 U[NL * NQ][4];
    const int t = threadIdx.x;

    for (int k = t; k < DIM; k += 1024) st[k] = make_float2(k == 0 ? 1.f : 0.f, 0.f);

    if (t < NL * NQ) {
        float phi = params[t * 3 + 0], th = params[t * 3 + 1], lam = params[t * 3 + 2];
        float c = cosf(0.5f * th), s = sinf(0.5f * th);
        float ap = 0.5f * (lam + phi), am = 0.5f * (lam - phi);
        // M = U^T, U = Rz(lam) Ry(th) Rz(phi)
        U[t][0] = make_float2(c * cosf(ap), -c * sinf(ap));
        U[t][1] = make_float2(s * cosf(am), s * sinf(am));
        U[t][2] = make_float2(-s * cosf(am), s * sinf(am));
        U[t][3] = make_float2(c * cosf(ap), c * sinf(ap));
    }
    __syncthreads();

    for (int l = 0; l < NL; ++l) {
        for (int qq = 0; qq < NQ; qq += 2) {
            const float2* M1 = U[l * NQ + qq];
            const float2* M2 = U[l * NQ + qq + 1];
            const int b2 = 10 - qq;              // bit of qubit qq+1
            const int s2 = 1 << b2, s1 = s2 << 1;
            int hi = t >> b2, lo = t & (s2 - 1);
            int i00 = (hi << (b2 + 2)) | lo;
            int i01 = i00 + s2, i10 = i00 + s1, i11 = i10 + s2;
            float2 a00 = st[i00], a01 = st[i01], a10 = st[i10], a11 = st[i11];
            float2 b00 = cadd(cmul(M1[0], a00), cmul(M1[1], a10));
            float2 b10 = cadd(cmul(M1[2], a00), cmul(M1[3], a10));
            float2 b01 = cadd(cmul(M1[0], a01), cmul(M1[1], a11));
            float2 b11 = cadd(cmul(M1[2], a01), cmul(M1[3], a11));
            st[i00] = cadd(cmul(M2[0], b00), cmul(M2[1], b01));
            st[i01] = cadd(cmul(M2[2], b00), cmul(M2[3], b01));
            st[i10] = cadd(cmul(M2[0], b10), cmul(M2[1], b11));
            st[i11] = cadd(cmul(M2[2], b10), cmul(M2[3], b11));
            __syncthreads();
        }
        if (l < NL - 1) {
            float2 v[4];
            #pragma unroll
            for (int u = 0; u < 4; ++u) {
                int k = t * 4 + u, j = k;
                #pragma unroll
                for (int q = 10; q >= 0; --q) j ^= ((j >> (11 - q)) & 1) << (10 - q);
                v[u] = st[j];
            }
            __syncthreads();
            #pragma unroll
            for (int u = 0; u < 4; ++u) st[t * 4 + u] = v[u];
            __syncthreads();
        }
    }
    for (int k = t; k < DIM; k += 1024) psi1[k] = st[k];
}

// ---------------------------------------------------------------------------
// Kernel B: per-batch data gates. The final CNOT-chain/bit-reverse output
// permutation is DROPPED (K invariant under column permutations of S).
// ---------------------------------------------------------------------------
__global__ __launch_bounds__(1024) void qnn_states(const float* __restrict__ X,
                                                   const float2* __restrict__ psi1,
                                                   u16* __restrict__ R,
                                                   u16* __restrict__ I) {
    __shared__ float2 st[DIM];
    __shared__ float cs[NQ], sn[NQ];
    const int b = blockIdx.x;
    const int t = threadIdx.x;

    for (int k = t; k < DIM; k += 1024) st[k] = psi1[k];
    if (t < NQ) {
        float a = 0.5f * X[b * NQ + t];
        cs[t] = cosf(a); sn[t] = sinf(a);
    }
    __syncthreads();

    for (int qq = 0; qq < NQ; qq += 2) {
        const float c1 = cs[qq], s1v = sn[qq];
        const float c2 = cs[qq + 1], s2v = sn[qq + 1];
        const int b2 = 10 - qq;
        const int s2 = 1 << b2, s1 = s2 << 1;
        int hi = t >> b2, lo = t & (s2 - 1);
        int i00 = (hi << (b2 + 2)) | lo;
        int i01 = i00 + s2, i10 = i00 + s1, i11 = i10 + s2;
        float2 a00 = st[i00], a01 = st[i01], a10 = st[i10], a11 = st[i11];
        float2 b00 = make_float2(c1 * a00.x + s1v * a10.x, c1 * a00.y + s1v * a10.y);
        float2 b10 = make_float2(-s1v * a00.x + c1 * a10.x, -s1v * a00.y + c1 * a10.y);
        float2 b01 = make_float2(c1 * a01.x + s1v * a11.x, c1 * a01.y + s1v * a11.y);
        float2 b11 = make_float2(-s1v * a01.x + c1 * a11.x, -s1v * a01.y + c1 * a11.y);
        st[i00] = make_float2(c2 * b00.x + s2v * b01.x, c2 * b00.y + s2v * b01.y);
        st[i01] = make_float2(-s2v * b00.x + c2 * b01.x, -s2v * b00.y + c2 * b01.y);
        st[i10] = make_float2(c2 * b10.x + s2v * b11.x, c2 * b10.y + s2v * b11.y);
        st[i11] = make_float2(-s2v * b10.x + c2 * b11.x, -s2v * b10.y + c2 * b11.y);
        __syncthreads();
    }

    u16 hr[4], hi4[4];
    #pragma unroll
    for (int u = 0; u < 4; ++u) {
        float2 a = st[t * 4 + u];
        hr[u] = f32_to_bf16_bits(a.x);
        hi4[u] = f32_to_bf16_bits(a.y);
    }
    *(ushort4*)&R[(size_t)b * DIM + t * 4] = make_ushort4(hr[0], hr[1], hr[2], hr[3]);
    *(ushort4*)&I[(size_t)b * DIM + t * 4] = make_ushort4(hi4[0], hi4[1], hi4[2], hi4[3]);
}

// ---------------------------------------------------------------------------
// Kernel C: K = |S S^H|^2 — R0 loop order, but BK=32 with a SINGLE 32 KB
// buffer (m97 recipe): LDS 32 KB + VGPR ~116 -> 4 blocks/CU co-resident,
// 4 waves/SIMD whose independent phases cover each other's drain stalls
// (m97/m103 sustain 14 TB/s staged this way vs our 6.2 at 2 blocks/CU).
// NO forced min-occupancy (R3 lesson: launch_bounds(256,3) spilled acc).
// XCD-aware bijective swizzle kept (R5: -37% HBM fetch, free).
// Per iter: barrier(drain) -> frag reads -> barrier -> ISSUE(it+1)
// -> 32-MFMA stream grouped by term.
// LDS: 4 planes [A-Re, A-Im, B-Re, B-Im][128 rows][64 B];
// chunk swizzle phys = logchunk ^ ((row>>1)&3).
// ---------------------------------------------------------------------------
__global__ __launch_bounds__(256, 2) void qnn_gram(const u16* __restrict__ Rm,
                                                   const u16* __restrict__ Im,
                                                   float* __restrict__ K) {
    // XCD swizzle: contiguous run of 66 tiles per XCD (bijective, 528%8==0).
    const int p = (blockIdx.x % NXCD) * CPX + blockIdx.x / NXCD;
    int bi, bj;
    tile_of(p, &bi, &bj);

    __shared__ __align__(16) unsigned char lds[4][TILE][64];   // 32 KB
    const int t = threadIdx.x;
    const int w = t >> 6, lane = t & 63;
    const int half = lane >> 5, l31 = lane & 31;
    const int wm = (w >> 1) * 64, wn = (w & 1) * 64;
    const int rowA = bi * TILE, rowB = bj * TILE;
    const int srow16 = lane >> 2;   // 0..15
    const int sphys = lane & 3;

    f32x16 accRe[2][2], accIm[2][2];
    #pragma unroll
    for (int a = 0; a < 2; ++a)
        #pragma unroll
        for (int b = 0; b < 2; ++b) {
            #pragma unroll
            for (int r = 0; r < 16; ++r) { accRe[a][b][r] = 0.f; accIm[a][b][r] = 0.f; }
        }

    // staging per plane pl: 8 slots (s = w*2+jj) x 16 rows x 64 B;
    // lane -> row = s*16 + (lane>>2), phys chunk = lane&3 (HW dest lane*16),
    // global logchunk = (lane&3) ^ ((row>>1)&3). 8 instr/wave per iter.
#define ISSUE(it)                                                                       \
    do {                                                                                \
        const size_t kbase = (size_t)(it) * (BK * 2);                                   \
        _Pragma("unroll")                                                               \
        for (int pl = 0; pl < 4; ++pl) {                                                \
            const u16* src = (pl & 1) ? Im : Rm;                                        \
            const int rb = (pl < 2) ? rowA : rowB;                                      \
            _Pragma("unroll")                                                           \
            for (int jj = 0; jj < 2; ++jj) {                                            \
                int s = w * 2 + jj;                                                     \
                int row = s * 16 + srow16;                                              \
                int logc = sphys ^ ((row >> 1) & 3);                                    \
                const char* gp = (const char*)src                                       \
                    + (size_t)(rb + row) * (DIM * 2) + kbase + logc * 16;               \
                char* lp = (char*)lds + pl * 8192 + s * 1024;                           \
                async_copy16(gp, lp);                                                   \
            }                                                                           \
        }                                                                               \
    } while (0)

    ISSUE(0);
    for (int it = 0; it < NIT; ++it) {
        __syncthreads();   // drains vmcnt: buffer holds iter 'it'

        // frags: A[m = l31][k = g*16 + half*8 + j] -> chunk = g*2+half (swizzled)
        bf16x8 fRA[2][2], fIA[2][2], fRB[2][2], fIB[2][2], fRAn[2][2];
        #pragma unroll
        for (int mi = 0; mi < 2; ++mi) {
            int r = wm + mi * 32 + l31;
            int sw = (r >> 1) & 3;
            #pragma unroll
            for (int g = 0; g < 2; ++g) {
                int phys = ((g * 2 + half) ^ sw);
                fRA[mi][g] = *(const bf16x8*)((const char*)lds + 0 * 8192 + r * 64 + phys * 16);
                fIA[mi][g] = *(const bf16x8*)((const char*)lds + 1 * 8192 + r * 64 + phys * 16);
                u32x4 ran = __builtin_bit_cast(u32x4, fRA[mi][g]) ^ 0x80008000u;
                fRAn[mi][g] = __builtin_bit_cast(bf16x8, ran);
            }
        }
        #pragma unroll
        for (int ni = 0; ni < 2; ++ni) {
            int r = wn + ni * 32 + l31;
            int sw = (r >> 1) & 3;
            #pragma unroll
            for (int g = 0; g < 2; ++g) {
                int phys = ((g * 2 + half) ^ sw);
                fRB[ni][g] = *(const bf16x8*)((const char*)lds + 2 * 8192 + r * 64 + phys * 16);
                fIB[ni][g] = *(const bf16x8*)((const char*)lds + 3 * 8192 + r * 64 + phys * 16);
            }
        }

        __syncthreads();   // all waves done reading LDS
        if (it + 1 < NIT) ISSUE(it + 1);   // overlaps the MFMA stream below

        // grouped by term: same-accumulator reuse distance = 4 MFMAs
        #pragma unroll
        for (int g = 0; g < 2; ++g) {
            #pragma unroll
            for (int mi = 0; mi < 2; ++mi)
                #pragma unroll
                for (int ni = 0; ni < 2; ++ni)
                    accRe[mi][ni] = MFMA32(fRA[mi][g], fRB[ni][g], accRe[mi][ni]);
            #pragma unroll
            for (int mi = 0; mi < 2; ++mi)
                #pragma unroll
                for (int ni = 0; ni < 2; ++ni)
                    accIm[mi][ni] = MFMA32(fIA[mi][g], fRB[ni][g], accIm[mi][ni]);
            #pragma unroll
            for (int mi = 0; mi < 2; ++mi)
                #pragma unroll
                for (int ni = 0; ni < 2; ++ni)
                    accRe[mi][ni] = MFMA32(fIA[mi][g], fIB[ni][g], accRe[mi][ni]);
            #pragma unroll
            for (int mi = 0; mi < 2; ++mi)
                #pragma unroll
                for (int ni = 0; ni < 2; ++ni)
                    accIm[mi][ni] = MFMA32(fRAn[mi][g], fIB[ni][g], accIm[mi][ni]);
        }
    }
#undef ISSUE

    // epilogue: C/D 32x32 layout col=lane&31, row=(reg&3)+8*(reg>>2)+4*(lane>>5)
    const int iBase = rowA + wm;
    const int jBase = rowB + wn;
    #pragma unroll
    for (int mi = 0; mi < 2; ++mi)
        #pragma unroll
        for (int ni = 0; ni < 2; ++ni)
            #pragma unroll
            for (int r = 0; r < 16; ++r) {
                int row32 = (r & 3) + 8 * (r >> 2) + 4 * half;
                int i = iBase + mi * 32 + row32;
                int j = jBase + ni * 32 + l31;
                float re = accRe[mi][ni][r];
                float im = accIm[mi][ni][r];
                float v = re * re + im * im;
                if (i == j) v = 1.0f;
                K[(size_t)i * BATCH + j] = v;
                if (bi != bj) K[(size_t)j * BATCH + i] = v;
            }
}

extern "C" void kernel_launch(void* const* d_in, const int* in_sizes, int n_in,
                              void* d_out, int out_size, void* d_ws, size_t ws_size,
                              hipStream_t stream) {
    const float* X = (const float*)d_in[0];
    const float* params = (const float*)d_in[1];

    float2* psi1 = (float2*)d_ws;
    u16* R = (u16*)((char*)d_ws + 65536);
    u16* I = R + (size_t)BATCH * DIM;
    float* K = (float*)d_out;

    hipLaunchKernelGGL(qnn_base, dim3(1), dim3(1024), 0, stream, params, psi1);
    hipLaunchKernelGGL(qnn_states, dim3(BATCH), dim3(1024), 0, stream, X, psi1, R, I);
    hipLaunchKernelGGL(qnn_gram, dim3(NBLK), dim3(256), 0, stream, R, I, K);
}

// Round 7
// 526.657 us; speedup vs baseline: 1.0092x; 1.0092x over previous
//
#include <hip/hip_runtime.h>
#include <hip/hip_bf16.h>

#define NQ 12
#define NL 5
#define DIM 4096
#define BATCH 4096
#define TILE 128
#define BK 32
#define NIT (DIM / BK)                  // 128
#define NTILE (BATCH / TILE)            // 32
#define NBLK (NTILE * (NTILE + 1) / 2)  // 528
#define NXCD 8
#define CPX (NBLK / NXCD)               // 66, exact -> bijective swizzle

typedef __bf16 bf16x8 __attribute__((ext_vector_type(8)));
typedef float f32x16 __attribute__((ext_vector_type(16)));
typedef unsigned int u32x4 __attribute__((ext_vector_type(4)));
typedef unsigned int u32;
typedef unsigned short u16;

#define MFMA32(a, b, c) __builtin_amdgcn_mfma_f32_32x32x16_bf16(a, b, c, 0, 0, 0)

// float -> bf16 bits, round-to-nearest-even
__device__ static inline u16 f32_to_bf16_bits(float x) {
    u32 b = __builtin_bit_cast(u32, x);
    b += 0x7fffu + ((b >> 16) & 1u);
    return (u16)(b >> 16);
}

// async 16B global->LDS; HW writes wave-uniform lds base + lane*16.
__device__ static inline void async_copy16(const void* g, void* l) {
    __builtin_amdgcn_global_load_lds((const __attribute__((address_space(1))) u32*)g,
                                     (__attribute__((address_space(3))) u32*)l, 16, 0, 0);
}

// complex helpers
__device__ static inline float2 cmul(float2 m, float2 a) {
    return make_float2(m.x * a.x - m.y * a.y, m.x * a.y + m.y * a.x);
}
__device__ static inline float2 cadd(float2 a, float2 b) {
    return make_float2(a.x + b.x, a.y + b.y);
}

// tile index p (0..527) -> (bi, bj), bi <= bj
__device__ static inline void tile_of(int p, int* bi, int* bj) {
    int rem = p, b = 0;
    while (rem >= NTILE - b) { rem -= NTILE - b; ++b; }
    *bi = b; *bj = b + rem;
}

// ---------------------------------------------------------------------------
// Kernel A: batch-independent part (layers 0..3 full, layer 4 param gates).
// ---------------------------------------------------------------------------
__global__ __launch_bounds__(1024) void qnn_base(const float* __restrict__ params,
                                                 float2* __restrict__ psi1) {
    __shared__ float2 st[DIM];
    __shared__ float2 U[NL * NQ][4];
    const int t = threadIdx.x;

    for (int k = t; k < DIM; k += 1024) st[k] = make_float2(k == 0 ? 1.f : 0.f, 0.f);

    if (t < NL * NQ) {
        float phi = params[t * 3 + 0], th = params[t * 3 + 1], lam = params[t * 3 + 2];
        float c = cosf(0.5f * th), s = sinf(0.5f * th);
        float ap = 0.5f * (lam + phi), am = 0.5f * (lam - phi);
        // M = U^T, U = Rz(lam) Ry(th) Rz(phi)
        U[t][0] = make_float2(c * cosf(ap), -c * sinf(ap));
        U[t][1] = make_float2(s * cosf(am), s * sinf(am));
        U[t][2] = make_float2(-s * cosf(am), s * sinf(am));
        U[t][3] = make_float2(c * cosf(ap), c * sinf(ap));
    }
    __syncthreads();

    for (int l = 0; l < NL; ++l) {
        for (int qq = 0; qq < NQ; qq += 2) {
            const float2* M1 = U[l * NQ + qq];
            const float2* M2 = U[l * NQ + qq + 1];
            const int b2 = 10 - qq;              // bit of qubit qq+1
            const int s2 = 1 << b2, s1 = s2 << 1;
            int hi = t >> b2, lo = t & (s2 - 1);
            int i00 = (hi << (b2 + 2)) | lo;
            int i01 = i00 + s2, i10 = i00 + s1, i11 = i10 + s2;
            float2 a00 = st[i00], a01 = st[i01], a10 = st[i10], a11 = st[i11];
            float2 b00 = cadd(cmul(M1[0], a00), cmul(M1[1], a10));
            float2 b10 = cadd(cmul(M1[2], a00), cmul(M1[3], a10));
            float2 b01 = cadd(cmul(M1[0], a01), cmul(M1[1], a11));
            float2 b11 = cadd(cmul(M1[2], a01), cmul(M1[3], a11));
            st[i00] = cadd(cmul(M2[0], b00), cmul(M2[1], b01));
            st[i01] = cadd(cmul(M2[2], b00), cmul(M2[3], b01));
            st[i10] = cadd(cmul(M2[0], b10), cmul(M2[1], b11));
            st[i11] = cadd(cmul(M2[2], b10), cmul(M2[3], b11));
            __syncthreads();
        }
        if (l < NL - 1) {
            float2 v[4];
            #pragma unroll
            for (int u = 0; u < 4; ++u) {
                int k = t * 4 + u, j = k;
                #pragma unroll
                for (int q = 10; q >= 0; --q) j ^= ((j >> (11 - q)) & 1) << (10 - q);
                v[u] = st[j];
            }
            __syncthreads();
            #pragma unroll
            for (int u = 0; u < 4; ++u) st[t * 4 + u] = v[u];
            __syncthreads();
        }
    }
    for (int k = t; k < DIM; k += 1024) psi1[k] = st[k];
}

// ---------------------------------------------------------------------------
// Kernel B: per-batch data gates. The final CNOT-chain/bit-reverse output
// permutation is DROPPED (K invariant under column permutations of S).
// ---------------------------------------------------------------------------
__global__ __launch_bounds__(1024) void qnn_states(const float* __restrict__ X,
                                                   const float2* __restrict__ psi1,
                                                   u16* __restrict__ R,
                                                   u16* __restrict__ I) {
    __shared__ float2 st[DIM];
    __shared__ float cs[NQ], sn[NQ];
    const int b = blockIdx.x;
    const int t = threadIdx.x;

    for (int k = t; k < DIM; k += 1024) st[k] = psi1[k];
    if (t < NQ) {
        float a = 0.5f * X[b * NQ + t];
        cs[t] = cosf(a); sn[t] = sinf(a);
    }
    __syncthreads();

    for (int qq = 0; qq < NQ; qq += 2) {
        const float c1 = cs[qq], s1v = sn[qq];
        const float c2 = cs[qq + 1], s2v = sn[qq + 1];
        const int b2 = 10 - qq;
        const int s2 = 1 << b2, s1 = s2 << 1;
        int hi = t >> b2, lo = t & (s2 - 1);
        int i00 = (hi << (b2 + 2)) | lo;
        int i01 = i00 + s2, i10 = i00 + s1, i11 = i10 + s2;
        float2 a00 = st[i00], a01 = st[i01], a10 = st[i10], a11 = st[i11];
        float2 b00 = make_float2(c1 * a00.x + s1v * a10.x, c1 * a00.y + s1v * a10.y);
        float2 b10 = make_float2(-s1v * a00.x + c1 * a10.x, -s1v * a00.y + c1 * a10.y);
        float2 b01 = make_float2(c1 * a01.x + s1v * a11.x, c1 * a01.y + s1v * a11.y);
        float2 b11 = make_float2(-s1v * a01.x + c1 * a11.x, -s1v * a01.y + c1 * a11.y);
        st[i00] = make_float2(c2 * b00.x + s2v * b01.x, c2 * b00.y + s2v * b01.y);
        st[i01] = make_float2(-s2v * b00.x + c2 * b01.x, -s2v * b00.y + c2 * b01.y);
        st[i10] = make_float2(c2 * b10.x + s2v * b11.x, c2 * b10.y + s2v * b11.y);
        st[i11] = make_float2(-s2v * b10.x + c2 * b11.x, -s2v * b10.y + c2 * b11.y);
        __syncthreads();
    }

    u16 hr[4], hi4[4];
    #pragma unroll
    for (int u = 0; u < 4; ++u) {
        float2 a = st[t * 4 + u];
        hr[u] = f32_to_bf16_bits(a.x);
        hi4[u] = f32_to_bf16_bits(a.y);
    }
    *(ushort4*)&R[(size_t)b * DIM + t * 4] = make_ushort4(hr[0], hr[1], hr[2], hr[3]);
    *(ushort4*)&I[(size_t)b * DIM + t * 4] = make_ushort4(hi4[0], hi4[1], hi4[2], hi4[3]);
}

// ---------------------------------------------------------------------------
// Kernel C: K = |S S^H|^2 — T3/T4 counted-vmcnt pipeline.
// BK=32, DOUBLE buffer (2 x 32 KB = 64 KB, 2 blocks/CU as R0), depth-2
// prefetch. Per iter (reading buf c = it&1):
//   s_waitcnt vmcnt(8) + s_barrier   <- only the OLDEST 8 loads (buf c);
//                                       the 8 for buf c^1 stay in flight
//   READF(c)                          <- 16 ds_read_b128
//   s_waitcnt lgkmcnt(0) + s_barrier  <- all waves done reading c
//   ISSUE(it+2 -> c)                  <- refill c, 2 iters ahead
//   32 MFMA (setprio 1)
// Issue->wait distance = 2 iterations (~5k cyc) -> load latency hidden.
// This is the m218 "counted vs drain0" lever (+38-73%) that R2 (vmcnt(0),
// depth-1) never tested. XCD-aware bijective swizzle kept (R5: -37% HBM).
// LDS per buffer: 4 planes [A-Re, A-Im, B-Re, B-Im][128 rows][64 B];
// chunk swizzle phys = logchunk ^ ((row>>1)&3) (verified, both-sides).
// ---------------------------------------------------------------------------
__global__ __launch_bounds__(256, 2) void qnn_gram(const u16* __restrict__ Rm,
                                                   const u16* __restrict__ Im,
                                                   float* __restrict__ K) {
    // XCD swizzle: contiguous run of 66 tiles per XCD (bijective, 528%8==0).
    const int p = (blockIdx.x % NXCD) * CPX + blockIdx.x / NXCD;
    int bi, bj;
    tile_of(p, &bi, &bj);

    __shared__ __align__(16) unsigned char lds[2][4][TILE][64];   // 64 KB
    const int t = threadIdx.x;
    const int w = t >> 6, lane = t & 63;
    const int half = lane >> 5, l31 = lane & 31;
    const int wm = (w >> 1) * 64, wn = (w & 1) * 64;
    const int rowA = bi * TILE, rowB = bj * TILE;
    const int srow16 = lane >> 2;   // 0..15
    const int sphys = lane & 3;

    f32x16 accRe[2][2], accIm[2][2];
    #pragma unroll
    for (int a = 0; a < 2; ++a)
        #pragma unroll
        for (int b = 0; b < 2; ++b) {
            #pragma unroll
            for (int r = 0; r < 16; ++r) { accRe[a][b][r] = 0.f; accIm[a][b][r] = 0.f; }
        }

    // staging per plane pl: 8 slots (s = w*2+jj) x 16 rows x 64 B;
    // lane -> row = s*16 + (lane>>2), phys chunk = lane&3 (HW dest lane*16),
    // global logchunk = (lane&3) ^ ((row>>1)&3). 8 instr/thread per ISSUE.
#define ISSUE(it, c)                                                                    \
    do {                                                                                \
        const size_t kbase = (size_t)(it) * (BK * 2);                                   \
        _Pragma("unroll")                                                               \
        for (int pl = 0; pl < 4; ++pl) {                                                \
            const u16* src = (pl & 1) ? Im : Rm;                                        \
            const int rb = (pl < 2) ? rowA : rowB;                                      \
            _Pragma("unroll")                                                           \
            for (int jj = 0; jj < 2; ++jj) {                                            \
                int s = w * 2 + jj;                                                     \
                int row = s * 16 + srow16;                                              \
                int logc = sphys ^ ((row >> 1) & 3);                                    \
                const char* gp = (const char*)src                                       \
                    + (size_t)(rb + row) * (DIM * 2) + kbase + logc * 16;               \
                char* lp = (char*)lds + (c) * 32768 + pl * 8192 + s * 1024;             \
                async_copy16(gp, lp);                                                   \
            }                                                                           \
        }                                                                               \
    } while (0)

    ISSUE(0, 0);
    ISSUE(1, 1);
    for (int it = 0; it < NIT; ++it) {
        const int c = it & 1;
        // wait ONLY the oldest batch (buf c); newer 8 stay in flight
        if (it + 1 < NIT) asm volatile("s_waitcnt vmcnt(8)\ns_barrier" ::: "memory");
        else              asm volatile("s_waitcnt vmcnt(0)\ns_barrier" ::: "memory");

        // frags: A[m = l31][k = g*16 + half*8 + j] -> chunk = g*2+half (swizzled)
        bf16x8 fRA[2][2], fIA[2][2], fRB[2][2], fIB[2][2], fRAn[2][2];
        #pragma unroll
        for (int mi = 0; mi < 2; ++mi) {
            int r = wm + mi * 32 + l31;
            int sw = (r >> 1) & 3;
            #pragma unroll
            for (int g = 0; g < 2; ++g) {
                int phys = ((g * 2 + half) ^ sw);
                fRA[mi][g] = *(const bf16x8*)((const char*)lds + c * 32768 + 0 * 8192 + r * 64 + phys * 16);
                fIA[mi][g] = *(const bf16x8*)((const char*)lds + c * 32768 + 1 * 8192 + r * 64 + phys * 16);
                u32x4 ran = __builtin_bit_cast(u32x4, fRA[mi][g]) ^ 0x80008000u;
                fRAn[mi][g] = __builtin_bit_cast(bf16x8, ran);
            }
        }
        #pragma unroll
        for (int ni = 0; ni < 2; ++ni) {
            int r = wn + ni * 32 + l31;
            int sw = (r >> 1) & 3;
            #pragma unroll
            for (int g = 0; g < 2; ++g) {
                int phys = ((g * 2 + half) ^ sw);
                fRB[ni][g] = *(const bf16x8*)((const char*)lds + c * 32768 + 2 * 8192 + r * 64 + phys * 16);
                fIB[ni][g] = *(const bf16x8*)((const char*)lds + c * 32768 + 3 * 8192 + r * 64 + phys * 16);
            }
        }

        // all waves done reading buf c -> c refillable
        asm volatile("s_waitcnt lgkmcnt(0)\ns_barrier" ::: "memory");
        if (it + 2 < NIT) ISSUE(it + 2, c);

        __builtin_amdgcn_s_setprio(1);
        // grouped by term: same-accumulator reuse distance = 4 MFMAs
        #pragma unroll
        for (int g = 0; g < 2; ++g) {
            #pragma unroll
            for (int mi = 0; mi < 2; ++mi)
                #pragma unroll
                for (int ni = 0; ni < 2; ++ni)
                    accRe[mi][ni] = MFMA32(fRA[mi][g], fRB[ni][g], accRe[mi][ni]);
            #pragma unroll
            for (int mi = 0; mi < 2; ++mi)
                #pragma unroll
                for (int ni = 0; ni < 2; ++ni)
                    accIm[mi][ni] = MFMA32(fIA[mi][g], fRB[ni][g], accIm[mi][ni]);
            #pragma unroll
            for (int mi = 0; mi < 2; ++mi)
                #pragma unroll
                for (int ni = 0; ni < 2; ++ni)
                    accRe[mi][ni] = MFMA32(fIA[mi][g], fIB[ni][g], accRe[mi][ni]);
            #pragma unroll
            for (int mi = 0; mi < 2; ++mi)
                #pragma unroll
                for (int ni = 0; ni < 2; ++ni)
                    accIm[mi][ni] = MFMA32(fRAn[mi][g], fIB[ni][g], accIm[mi][ni]);
        }
        __builtin_amdgcn_s_setprio(0);
    }
#undef ISSUE

    // epilogue: C/D 32x32 layout col=lane&31, row=(reg&3)+8*(reg>>2)+4*(lane>>5)
    const int iBase = rowA + wm;
    const int jBase = rowB + wn;
    #pragma unroll
    for (int mi = 0; mi < 2; ++mi)
        #pragma unroll
        for (int ni = 0; ni < 2; ++ni)
            #pragma unroll
            for (int r = 0; r < 16; ++r) {
                int row32 = (r & 3) + 8 * (r >> 2) + 4 * half;
                int i = iBase + mi * 32 + row32;
                int j = jBase + ni * 32 + l31;
                float re = accRe[mi][ni][r];
                float im = accIm[mi][ni][r];
                float v = re * re + im * im;
                if (i == j) v = 1.0f;
                K[(size_t)i * BATCH + j] = v;
                if (bi != bj) K[(size_t)j * BATCH + i] = v;
            }
}

extern "C" void kernel_launch(void* const* d_in, const int* in_sizes, int n_in,
                              void* d_out, int out_size, void* d_ws, size_t ws_size,
                              hipStream_t stream) {
    const float* X = (const float*)d_in[0];
    const float* params = (const float*)d_in[1];

    float2* psi1 = (float2*)d_ws;
    u16* R = (u16*)((char*)d_ws + 65536);
    u16* I = R + (size_t)BATCH * DIM;
    float* K = (float*)d_out;

    hipLaunchKernelGGL(qnn_base, dim3(1), dim3(1024), 0, stream, params, psi1);
    hipLaunchKernelGGL(qnn_states, dim3(BATCH), dim3(1024), 0, stream, X, psi1, R, I);
    hipLaunchKernelGGL(qnn_gram, dim3(NBLK), dim3(256), 0, stream, R, I, K);
}

// Round 8
// 419.555 us; speedup vs baseline: 1.2669x; 1.2553x over previous
//
#include <hip/hip_runtime.h>
#include <hip/hip_bf16.h>

#define NQ 12
#define NL 5
#define DIM 4096
#define BATCH 4096
#define TILE 128
#define BK 64
#define NIT (DIM / BK)                  // 64
#define NTILE (BATCH / TILE)            // 32
#define NBLK (NTILE * (NTILE + 1) / 2)  // 528

typedef __bf16 bf16x8 __attribute__((ext_vector_type(8)));
typedef float f32x16 __attribute__((ext_vector_type(16)));
typedef unsigned int u32x4 __attribute__((ext_vector_type(4)));
typedef unsigned int u32;
typedef unsigned short u16;

#define MFMA32(a, b, c) __builtin_amdgcn_mfma_f32_32x32x16_bf16(a, b, c, 0, 0, 0)

// float -> bf16 bits, round-to-nearest-even
__device__ static inline u16 f32_to_bf16_bits(float x) {
    u32 b = __builtin_bit_cast(u32, x);
    b += 0x7fffu + ((b >> 16) & 1u);
    return (u16)(b >> 16);
}

// async 16B global->LDS; HW writes wave-uniform lds base + lane*16.
__device__ static inline void async_copy16(const void* g, void* l) {
    __builtin_amdgcn_global_load_lds((const __attribute__((address_space(1))) u32*)g,
                                     (__attribute__((address_space(3))) u32*)l, 16, 0, 0);
}

// complex helpers
__device__ static inline float2 cmul(float2 m, float2 a) {
    return make_float2(m.x * a.x - m.y * a.y, m.x * a.y + m.y * a.x);
}
__device__ static inline float2 cadd(float2 a, float2 b) {
    return make_float2(a.x + b.x, a.y + b.y);
}

// tile index p (0..527) -> (bi, bj), bi <= bj
__device__ static inline void tile_of(int p, int* bi, int* bj) {
    int rem = p, b = 0;
    while (rem >= NTILE - b) { rem -= NTILE - b; ++b; }
    *bi = b; *bj = b + rem;
}

// ---------------------------------------------------------------------------
// Kernel A: batch-independent part (layers 0..3 full, layer 4 param gates).
// ---------------------------------------------------------------------------
__global__ __launch_bounds__(1024) void qnn_base(const float* __restrict__ params,
                                                 float2* __restrict__ psi1) {
    __shared__ float2 st[DIM];
    __shared__ float2 U[NL * NQ][4];
    const int t = threadIdx.x;

    for (int k = t; k < DIM; k += 1024) st[k] = make_float2(k == 0 ? 1.f : 0.f, 0.f);

    if (t < NL * NQ) {
        float phi = params[t * 3 + 0], th = params[t * 3 + 1], lam = params[t * 3 + 2];
        float c = cosf(0.5f * th), s = sinf(0.5f * th);
        float ap = 0.5f * (lam + phi), am = 0.5f * (lam - phi);
        // M = U^T, U = Rz(lam) Ry(th) Rz(phi)
        U[t][0] = make_float2(c * cosf(ap), -c * sinf(ap));
        U[t][1] = make_float2(s * cosf(am), s * sinf(am));
        U[t][2] = make_float2(-s * cosf(am), s * sinf(am));
        U[t][3] = make_float2(c * cosf(ap), c * sinf(ap));
    }
    __syncthreads();

    for (int l = 0; l < NL; ++l) {
        for (int qq = 0; qq < NQ; qq += 2) {
            const float2* M1 = U[l * NQ + qq];
            const float2* M2 = U[l * NQ + qq + 1];
            const int b2 = 10 - qq;              // bit of qubit qq+1
            const int s2 = 1 << b2, s1 = s2 << 1;
            int hi = t >> b2, lo = t & (s2 - 1);
            int i00 = (hi << (b2 + 2)) | lo;
            int i01 = i00 + s2, i10 = i00 + s1, i11 = i10 + s2;
            float2 a00 = st[i00], a01 = st[i01], a10 = st[i10], a11 = st[i11];
            float2 b00 = cadd(cmul(M1[0], a00), cmul(M1[1], a10));
            float2 b10 = cadd(cmul(M1[2], a00), cmul(M1[3], a10));
            float2 b01 = cadd(cmul(M1[0], a01), cmul(M1[1], a11));
            float2 b11 = cadd(cmul(M1[2], a01), cmul(M1[3], a11));
            st[i00] = cadd(cmul(M2[0], b00), cmul(M2[1], b01));
            st[i01] = cadd(cmul(M2[2], b00), cmul(M2[3], b01));
            st[i10] = cadd(cmul(M2[0], b10), cmul(M2[1], b11));
            st[i11] = cadd(cmul(M2[2], b10), cmul(M2[3], b11));
            __syncthreads();
        }
        if (l < NL - 1) {
            float2 v[4];
            #pragma unroll
            for (int u = 0; u < 4; ++u) {
                int k = t * 4 + u, j = k;
                #pragma unroll
                for (int q = 10; q >= 0; --q) j ^= ((j >> (11 - q)) & 1) << (10 - q);
                v[u] = st[j];
            }
            __syncthreads();
            #pragma unroll
            for (int u = 0; u < 4; ++u) st[t * 4 + u] = v[u];
            __syncthreads();
        }
    }
    for (int k = t; k < DIM; k += 1024) psi1[k] = st[k];
}

// ---------------------------------------------------------------------------
// NEW Kernel M: m_x = psi1^T J_x conj(psi1), x in [0,4096).
// (J_x v)_d = sign(d,x) v_{d^x}, sign = -1 iff popc(x & ~d) odd.
// Batch-independent; 256 blocks x 16 x-values.
// ---------------------------------------------------------------------------
__global__ __launch_bounds__(256) void qnn_m(const float2* __restrict__ psi1,
                                             float2* __restrict__ m) {
    __shared__ float2 st[DIM];
    __shared__ float2 red[4];
    const int t = threadIdx.x;
    for (int k = t; k < DIM; k += 256) st[k] = psi1[k];
    __syncthreads();
    for (int xi = 0; xi < 16; ++xi) {
        const int x = blockIdx.x * 16 + xi;
        float sre = 0.f, sim = 0.f;
        for (int d = t; d < DIM; d += 256) {
            float2 a = st[d];
            float2 b = st[d ^ x];
            float sgn = (__popc(x & ~d) & 1) ? -1.f : 1.f;
            sre += sgn * (a.x * b.x + a.y * b.y);   // a * conj(b)
            sim += sgn * (a.y * b.x - a.x * b.y);
        }
        #pragma unroll
        for (int o = 32; o; o >>= 1) {
            sre += __shfl_down(sre, o);
            sim += __shfl_down(sim, o);
        }
        if ((t & 63) == 0) red[t >> 6] = make_float2(sre, sim);
        __syncthreads();
        if (t == 0)
            m[x] = make_float2(red[0].x + red[1].x + red[2].x + red[3].x,
                               red[0].y + red[1].y + red[2].y + red[3].y);
        __syncthreads();
    }
}

// ---------------------------------------------------------------------------
// NEW Kernel B': per batch b, w(b) = (tensor_q B(a_bq)) m with symmetric
// B = [[c,s],[s,-c]] (12 butterflies, qubit q on bit 11-q), and
// u(b) = tensor_q (c_q, s_q). Then G_bb' = u(b') . w(b) -> only 2 real
// MFMA terms in the Gram. No output permutation needed.
// ---------------------------------------------------------------------------
__global__ __launch_bounds__(1024) void qnn_wu(const float* __restrict__ X,
                                               const float2* __restrict__ m,
                                               u16* __restrict__ WR,
                                               u16* __restrict__ WI,
                                               u16* __restrict__ Uo) {
    __shared__ float2 st[DIM];
    __shared__ float cs[NQ], sn[NQ];
    const int b = blockIdx.x;
    const int t = threadIdx.x;

    for (int k = t; k < DIM; k += 1024) st[k] = m[k];
    if (t < NQ) {
        float a = 0.5f * X[b * NQ + t];
        cs[t] = cosf(a); sn[t] = sinf(a);
    }
    __syncthreads();

    for (int qq = 0; qq < NQ; qq += 2) {
        const float c1 = cs[qq], s1v = sn[qq];
        const float c2 = cs[qq + 1], s2v = sn[qq + 1];
        const int b2 = 10 - qq;
        const int s2 = 1 << b2, s1 = s2 << 1;
        int hi = t >> b2, lo = t & (s2 - 1);
        int i00 = (hi << (b2 + 2)) | lo;
        int i01 = i00 + s2, i10 = i00 + s1, i11 = i10 + s2;
        float2 a00 = st[i00], a01 = st[i01], a10 = st[i10], a11 = st[i11];
        // qubit qq: B = [[c,s],[s,-c]] on bit b2+1
        float2 b00 = make_float2(c1 * a00.x + s1v * a10.x, c1 * a00.y + s1v * a10.y);
        float2 b10 = make_float2(s1v * a00.x - c1 * a10.x, s1v * a00.y - c1 * a10.y);
        float2 b01 = make_float2(c1 * a01.x + s1v * a11.x, c1 * a01.y + s1v * a11.y);
        float2 b11 = make_float2(s1v * a01.x - c1 * a11.x, s1v * a01.y - c1 * a11.y);
        // qubit qq+1 on bit b2
        st[i00] = make_float2(c2 * b00.x + s2v * b01.x, c2 * b00.y + s2v * b01.y);
        st[i01] = make_float2(s2v * b00.x - c2 * b01.x, s2v * b00.y - c2 * b01.y);
        st[i10] = make_float2(c2 * b10.x + s2v * b11.x, c2 * b10.y + s2v * b11.y);
        st[i11] = make_float2(s2v * b10.x - c2 * b11.x, s2v * b10.y - c2 * b11.y);
        __syncthreads();
    }

    u16 hr[4], hi4[4], hu[4];
    #pragma unroll
    for (int u = 0; u < 4; ++u) {
        int y = t * 4 + u;
        float2 a = st[y];
        hr[u] = f32_to_bf16_bits(a.x);
        hi4[u] = f32_to_bf16_bits(a.y);
        float uu = 1.f;
        #pragma unroll
        for (int q = 0; q < NQ; ++q) uu *= ((y >> (11 - q)) & 1) ? sn[q] : cs[q];
        hu[u] = f32_to_bf16_bits(uu);
    }
    *(ushort4*)&WR[(size_t)b * DIM + t * 4] = make_ushort4(hr[0], hr[1], hr[2], hr[3]);
    *(ushort4*)&WI[(size_t)b * DIM + t * 4] = make_ushort4(hi4[0], hi4[1], hi4[2], hi4[3]);
    *(ushort4*)&Uo[(size_t)b * DIM + t * 4] = make_ushort4(hu[0], hu[1], hu[2], hu[3]);
}

// ---------------------------------------------------------------------------
// NEW Kernel C': Gram with 2 real terms. G_ij = sum_k u[j][k] w[i][k];
// K = Re^2 + Im^2. EXACT R0 loop structure (proven best), 3 planes
// [wRe_A, wIm_A, u_B] -> 6 sub-planes x [128][64B] = 48 KB LDS
// (3 blocks/CU fit naturally -> absorbs the 528-on-512 tail).
// Per iter: barrier(drain) -> frag reads -> barrier -> ISSUE(it+1)
// -> 32-MFMA stream grouped by term.
// chunk swizzle phys = logchunk ^ ((row>>1)&3) (verified conflict-free).
// ---------------------------------------------------------------------------
__global__ __launch_bounds__(256, 2) void qnn_gram2(const u16* __restrict__ WR,
                                                    const u16* __restrict__ WI,
                                                    const u16* __restrict__ Uo,
                                                    float* __restrict__ K) {
    int bi, bj;
    tile_of(blockIdx.x, &bi, &bj);

    __shared__ __align__(16) unsigned char lds[6][TILE][64];   // 48 KB
    const int t = threadIdx.x;
    const int w = t >> 6, lane = t & 63;
    const int half = lane >> 5, l31 = lane & 31;
    const int wm = (w >> 1) * 64, wn = (w & 1) * 64;
    const int rowA = bi * TILE, rowB = bj * TILE;
    const int srow16 = lane >> 2;   // 0..15
    const int sphys = lane & 3;

    f32x16 accRe[2][2], accIm[2][2];
    #pragma unroll
    for (int a = 0; a < 2; ++a)
        #pragma unroll
        for (int b = 0; b < 2; ++b) {
            #pragma unroll
            for (int r = 0; r < 16; ++r) { accRe[a][b][r] = 0.f; accIm[a][b][r] = 0.f; }
        }

#define ISSUE2(it)                                                                      \
    do {                                                                                \
        const size_t kbase = (size_t)(it) * (BK * 2);                                   \
        _Pragma("unroll")                                                               \
        for (int pl = 0; pl < 3; ++pl) {                                                \
            const u16* src = (pl == 0) ? WR : ((pl == 1) ? WI : Uo);                    \
            const int rb = (pl < 2) ? rowA : rowB;                                      \
            _Pragma("unroll")                                                           \
            for (int kh = 0; kh < 2; ++kh) {                                            \
                _Pragma("unroll")                                                       \
                for (int jj = 0; jj < 2; ++jj) {                                        \
                    int s = w * 2 + jj;                                                 \
                    int row = s * 16 + srow16;                                          \
                    int logc = sphys ^ ((row >> 1) & 3);                                \
                    const char* gp = (const char*)src                                   \
                        + (size_t)(rb + row) * (DIM * 2) + kbase + kh * 64              \
                        + logc * 16;                                                    \
                    char* lp = (char*)lds + (pl * 2 + kh) * 8192 + s * 1024;            \
                    async_copy16(gp, lp);                                               \
                }                                                                       \
            }                                                                           \
        }                                                                               \
    } while (0)

    ISSUE2(0);
    for (int it = 0; it < NIT; ++it) {
        __syncthreads();   // drains vmcnt: buffer holds iter 'it'

        bf16x8 fWR[2][4], fWI[2][4], fU[2][4];
        #pragma unroll
        for (int mi = 0; mi < 2; ++mi) {
            int r = wm + mi * 32 + l31;
            int sw = (r >> 1) & 3;
            #pragma unroll
            for (int k16 = 0; k16 < 4; ++k16) {
                int kh = k16 >> 1;
                int phys = (((k16 & 1) * 2 + half) ^ sw);
                fWR[mi][k16] = *(const bf16x8*)((const char*)lds + (0 + kh) * 8192 + r * 64 + phys * 16);
                fWI[mi][k16] = *(const bf16x8*)((const char*)lds + (2 + kh) * 8192 + r * 64 + phys * 16);
            }
        }
        #pragma unroll
        for (int ni = 0; ni < 2; ++ni) {
            int r = wn + ni * 32 + l31;
            int sw = (r >> 1) & 3;
            #pragma unroll
            for (int k16 = 0; k16 < 4; ++k16) {
                int kh = k16 >> 1;
                int phys = (((k16 & 1) * 2 + half) ^ sw);
                fU[ni][k16] = *(const bf16x8*)((const char*)lds + (4 + kh) * 8192 + r * 64 + phys * 16);
            }
        }

        __syncthreads();   // all waves done reading LDS
        if (it + 1 < NIT) ISSUE2(it + 1);   // overlaps the MFMA stream below

        // grouped by term: same-accumulator reuse distance = 4 MFMAs
        #pragma unroll
        for (int k16 = 0; k16 < 4; ++k16) {
            #pragma unroll
            for (int mi = 0; mi < 2; ++mi)
                #pragma unroll
                for (int ni = 0; ni < 2; ++ni)
                    accRe[mi][ni] = MFMA32(fWR[mi][k16], fU[ni][k16], accRe[mi][ni]);
            #pragma unroll
            for (int mi = 0; mi < 2; ++mi)
                #pragma unroll
                for (int ni = 0; ni < 2; ++ni)
                    accIm[mi][ni] = MFMA32(fWI[mi][k16], fU[ni][k16], accIm[mi][ni]);
        }
    }
#undef ISSUE2

    // epilogue: C/D 32x32 layout col=lane&31, row=(reg&3)+8*(reg>>2)+4*(lane>>5)
    const int iBase = rowA + wm;
    const int jBase = rowB + wn;
    #pragma unroll
    for (int mi = 0; mi < 2; ++mi)
        #pragma unroll
        for (int ni = 0; ni < 2; ++ni)
            #pragma unroll
            for (int r = 0; r < 16; ++r) {
                int row32 = (r & 3) + 8 * (r >> 2) + 4 * half;
                int i = iBase + mi * 32 + row32;
                int j = jBase + ni * 32 + l31;
                float re = accRe[mi][ni][r];
                float im = accIm[mi][ni][r];
                float v = re * re + im * im;
                if (i == j) v = 1.0f;
                K[(size_t)i * BATCH + j] = v;
                if (bi != bj) K[(size_t)j * BATCH + i] = v;
            }
}

// ---------------------------------------------------------------------------
// FALLBACK path (used only if ws_size is too small for the u/w planes):
// exact R0 kernels (proven 353 us gram).
// ---------------------------------------------------------------------------
__global__ __launch_bounds__(1024) void qnn_states(const float* __restrict__ X,
                                                   const float2* __restrict__ psi1,
                                                   u16* __restrict__ R,
                                                   u16* __restrict__ I) {
    __shared__ float2 st[DIM];
    __shared__ float cs[NQ], sn[NQ];
    const int b = blockIdx.x;
    const int t = threadIdx.x;

    for (int k = t; k < DIM; k += 1024) st[k] = psi1[k];
    if (t < NQ) {
        float a = 0.5f * X[b * NQ + t];
        cs[t] = cosf(a); sn[t] = sinf(a);
    }
    __syncthreads();

    for (int qq = 0; qq < NQ; qq += 2) {
        const float c1 = cs[qq], s1v = sn[qq];
        const float c2 = cs[qq + 1], s2v = sn[qq + 1];
        const int b2 = 10 - qq;
        const int s2 = 1 << b2, s1 = s2 << 1;
        int hi = t >> b2, lo = t & (s2 - 1);
        int i00 = (hi << (b2 + 2)) | lo;
        int i01 = i00 + s2, i10 = i00 + s1, i11 = i10 + s2;
        float2 a00 = st[i00], a01 = st[i01], a10 = st[i10], a11 = st[i11];
        float2 b00 = make_float2(c1 * a00.x + s1v * a10.x, c1 * a00.y + s1v * a10.y);
        float2 b10 = make_float2(-s1v * a00.x + c1 * a10.x, -s1v * a00.y + c1 * a10.y);
        float2 b01 = make_float2(c1 * a01.x + s1v * a11.x, c1 * a01.y + s1v * a11.y);
        float2 b11 = make_float2(-s1v * a01.x + c1 * a11.x, -s1v * a01.y + c1 * a11.y);
        st[i00] = make_float2(c2 * b00.x + s2v * b01.x, c2 * b00.y + s2v * b01.y);
        st[i01] = make_float2(-s2v * b00.x + c2 * b01.x, -s2v * b00.y + c2 * b01.y);
        st[i10] = make_float2(c2 * b10.x + s2v * b11.x, c2 * b10.y + s2v * b11.y);
        st[i11] = make_float2(-s2v * b10.x + c2 * b11.x, -s2v * b10.y + c2 * b11.y);
        __syncthreads();
    }

    u16 hr[4], hi4[4];
    #pragma unroll
    for (int u = 0; u < 4; ++u) {
        float2 a = st[t * 4 + u];
        hr[u] = f32_to_bf16_bits(a.x);
        hi4[u] = f32_to_bf16_bits(a.y);
    }
    *(ushort4*)&R[(size_t)b * DIM + t * 4] = make_ushort4(hr[0], hr[1], hr[2], hr[3]);
    *(ushort4*)&I[(size_t)b * DIM + t * 4] = make_ushort4(hi4[0], hi4[1], hi4[2], hi4[3]);
}

__global__ __launch_bounds__(256, 2) void qnn_gram(const u16* __restrict__ Rm,
                                                   const u16* __restrict__ Im,
                                                   float* __restrict__ K) {
    int bi, bj;
    tile_of(blockIdx.x, &bi, &bj);

    __shared__ __align__(16) unsigned char lds[8][TILE][64];
    const int t = threadIdx.x;
    const int w = t >> 6, lane = t & 63;
    const int half = lane >> 5, l31 = lane & 31;
    const int wm = (w >> 1) * 64, wn = (w & 1) * 64;
    const int rowA = bi * TILE, rowB = bj * TILE;
    const int srow16 = lane >> 2;
    const int sphys = lane & 3;

    f32x16 accRe[2][2], accIm[2][2];
    #pragma unroll
    for (int a = 0; a < 2; ++a)
        #pragma unroll
        for (int b = 0; b < 2; ++b) {
            #pragma unroll
            for (int r = 0; r < 16; ++r) { accRe[a][b][r] = 0.f; accIm[a][b][r] = 0.f; }
        }

#define ISSUE(it)                                                                       \
    do {                                                                                \
        const size_t kbase = (size_t)(it) * (BK * 2);                                   \
        _Pragma("unroll")                                                               \
        for (int pl = 0; pl < 4; ++pl) {                                                \
            const u16* src = (pl & 1) ? Im : Rm;                                        \
            const int rb = (pl < 2) ? rowA : rowB;                                      \
            _Pragma("unroll")                                                           \
            for (int kh = 0; kh < 2; ++kh) {                                            \
                _Pragma("unroll")                                                       \
                for (int jj = 0; jj < 2; ++jj) {                                        \
                    int s = w * 2 + jj;                                                 \
                    int row = s * 16 + srow16;                                          \
                    int logc = sphys ^ ((row >> 1) & 3);                                \
                    const char* gp = (const char*)src                                   \
                        + (size_t)(rb + row) * (DIM * 2) + kbase + kh * 64              \
                        + logc * 16;                                                    \
                    char* lp = (char*)lds + (pl * 2 + kh) * 8192 + s * 1024;            \
                    async_copy16(gp, lp);                                               \
                }                                                                       \
            }                                                                           \
        }                                                                               \
    } while (0)

    ISSUE(0);
    for (int it = 0; it < NIT; ++it) {
        __syncthreads();

        bf16x8 fRA[2][4], fIA[2][4], fRB[2][4], fIB[2][4], fRAn[2][4];
        #pragma unroll
        for (int mi = 0; mi < 2; ++mi) {
            int r = wm + mi * 32 + l31;
            int sw = (r >> 1) & 3;
            #pragma unroll
            for (int k16 = 0; k16 < 4; ++k16) {
                int kh = k16 >> 1;
                int phys = (((k16 & 1) * 2 + half) ^ sw);
                fRA[mi][k16] = *(const bf16x8*)((const char*)lds + (0 + kh) * 8192 + r * 64 + phys * 16);
                fIA[mi][k16] = *(const bf16x8*)((const char*)lds + (2 + kh) * 8192 + r * 64 + phys * 16);
                u32x4 ran = __builtin_bit_cast(u32x4, fRA[mi][k16]) ^ 0x80008000u;
                fRAn[mi][k16] = __builtin_bit_cast(bf16x8, ran);
            }
        }
        #pragma unroll
        for (int ni = 0; ni < 2; ++ni) {
            int r = wn + ni * 32 + l31;
            int sw = (r >> 1) & 3;
            #pragma unroll
            for (int k16 = 0; k16 < 4; ++k16) {
                int kh = k16 >> 1;
                int phys = (((k16 & 1) * 2 + half) ^ sw);
                fRB[ni][k16] = *(const bf16x8*)((const char*)lds + (4 + kh) * 8192 + r * 64 + phys * 16);
                fIB[ni][k16] = *(const bf16x8*)((const char*)lds + (6 + kh) * 8192 + r * 64 + phys * 16);
            }
        }

        __syncthreads();
        if (it + 1 < NIT) ISSUE(it + 1);

        #pragma unroll
        for (int k16 = 0; k16 < 4; ++k16) {
            #pragma unroll
            for (int mi = 0; mi < 2; ++mi)
                #pragma unroll
                for (int ni = 0; ni < 2; ++ni)
                    accRe[mi][ni] = MFMA32(fRA[mi][k16], fRB[ni][k16], accRe[mi][ni]);
            #pragma unroll
            for (int mi = 0; mi < 2; ++mi)
                #pragma unroll
                for (int ni = 0; ni < 2; ++ni)
                    accIm[mi][ni] = MFMA32(fIA[mi][k16], fRB[ni][k16], accIm[mi][ni]);
            #pragma unroll
            for (int mi = 0; mi < 2; ++mi)
                #pragma unroll
                for (int ni = 0; ni < 2; ++ni)
                    accRe[mi][ni] = MFMA32(fIA[mi][k16], fIB[ni][k16], accRe[mi][ni]);
            #pragma unroll
            for (int mi = 0; mi < 2; ++mi)
                #pragma unroll
                for (int ni = 0; ni < 2; ++ni)
                    accIm[mi][ni] = MFMA32(fRAn[mi][k16], fIB[ni][k16], accIm[mi][ni]);
        }
    }
#undef ISSUE

    const int iBase = rowA + wm;
    const int jBase = rowB + wn;
    #pragma unroll
    for (int mi = 0; mi < 2; ++mi)
        #pragma unroll
        for (int ni = 0; ni < 2; ++ni)
            #pragma unroll
            for (int r = 0; r < 16; ++r) {
                int row32 = (r & 3) + 8 * (r >> 2) + 4 * half;
                int i = iBase + mi * 32 + row32;
                int j = jBase + ni * 32 + l31;
                float re = accRe[mi][ni][r];
                float im = accIm[mi][ni][r];
                float v = re * re + im * im;
                if (i == j) v = 1.0f;
                K[(size_t)i * BATCH + j] = v;
                if (bi != bj) K[(size_t)j * BATCH + i] = v;
            }
}

extern "C" void kernel_launch(void* const* d_in, const int* in_sizes, int n_in,
                              void* d_out, int out_size, void* d_ws, size_t ws_size,
                              hipStream_t stream) {
    const float* X = (const float*)d_in[0];
    const float* params = (const float*)d_in[1];
    float* K = (float*)d_out;

    const size_t plane = (size_t)BATCH * DIM * sizeof(u16);   // 32 MB
    const size_t need = 131072 + 3 * plane;                   // 96 MB + 128 KB

    hipLaunchKernelGGL(qnn_base, dim3(1), dim3(1024), 0, stream, params,
                       (float2*)d_ws);

    if (ws_size >= need) {
        // new 2-term path: psi1 | m | WR | WI | U
        float2* psi1 = (float2*)d_ws;
        float2* m = (float2*)((char*)d_ws + 65536);
        u16* WR = (u16*)((char*)d_ws + 131072);
        u16* WI = (u16*)((char*)WR + plane);
        u16* Uo = (u16*)((char*)WI + plane);
        hipLaunchKernelGGL(qnn_m, dim3(256), dim3(256), 0, stream, psi1, m);
        hipLaunchKernelGGL(qnn_wu, dim3(BATCH), dim3(1024), 0, stream, X, m, WR, WI, Uo);
        hipLaunchKernelGGL(qnn_gram2, dim3(NBLK), dim3(256), 0, stream, WR, WI, Uo, K);
    } else {
        // fallback: exact R0 path
        float2* psi1 = (float2*)d_ws;
        u16* R = (u16*)((char*)d_ws + 65536);
        u16* I = R + (size_t)BATCH * DIM;
        hipLaunchKernelGGL(qnn_states, dim3(BATCH), dim3(1024), 0, stream, X, psi1, R, I);
        hipLaunchKernelGGL(qnn_gram, dim3(NBLK), dim3(256), 0, stream, R, I, K);
    }
}